// Round 5
// baseline (1998.748 us; speedup 1.0000x reference)
//
#include <hip/hip_runtime.h>
#include <stdint.h>

// ============================================================================
// LeapfrogIntegrator — round 6: occupancy push.
//   * sFeat shrunk 33.8KB -> 8.7KB via 4x 32-dim feature windows (sin/cos
//     halves x 2), mu exchange in 2 dim-half passes through same buffer.
//   * sWt stride 68 -> 64 (read pattern j*64+4c is 2-way/free), -2KB.
//   * sWr stride 20 -> 21 (q-groups now 16 banks apart: 4-way -> 2-way free).
//   Total LDS 78336 -> 51456 B  => 2-3 blocks/CU instead of 1.
//
// Integrator layout unchanged: lane(q,c) owns row c's dims [16q,16q+16).
// Friction: lane(q,c) accumulates gate for rows 4q..4q+3, dims 4c..4c+3,
// j sequential 0..127 (bit-identical to round-5 verified kernel).
// All exchanges intra-wave (per-wave feat buffer); s_waitcnt lgkmcnt(0)
// is a per-WAVE counter => guards lane-to-lane visibility inside the wave.
//
// Numerics: np op-order fp32 v-updates (contract off, IEEE division),
// fp64 x-chain with exact mod-2pi wrap, friction reuse, sigmoid identical.
// ============================================================================

#define HDT  0.05f
#define EPS  1e-8f
#define FRIC 0.05f

#define SU   68   // U row stride (words)
#define SWR  21   // W^T (dims x ranks) row stride  (was 20: 4-way conflict)
#define FST  34   // feature window row stride (words): 32 dims + 2 pad

__device__ __forceinline__ float bf1(uint16_t v){ return __builtin_bit_cast(float,(uint32_t)v<<16); }
__device__ __forceinline__ uint16_t rb16(float f){            // RNE bf16 pack
  uint32_t u=__builtin_bit_cast(uint32_t,f);
  return (uint16_t)((u + 0x7fffu + ((u>>16)&1u))>>16);
}
__device__ __forceinline__ float ldw(const void* p,int i,bool isbf){
  return isbf ? bf1(((const uint16_t*)p)[i]) : ((const float*)p)[i];
}

__device__ __forceinline__ void ld16(const void* p, size_t base, bool isbf, float* out){
  if(isbf){
    const uint16_t* pp=(const uint16_t*)p+base;
    uint4 a=*(const uint4*)pp, b=*(const uint4*)(pp+8);
    uint32_t w[8]={a.x,a.y,a.z,a.w,b.x,b.y,b.z,b.w};
    #pragma unroll
    for(int k=0;k<8;++k){
      out[2*k  ]=__builtin_bit_cast(float,w[k]<<16);
      out[2*k+1]=__builtin_bit_cast(float,w[k]&0xffff0000u);
    }
  } else {
    const float* pp=(const float*)p+base;
    #pragma unroll
    for(int k=0;k<4;++k){
      float4 t=((const float4*)pp)[k];
      out[4*k]=t.x; out[4*k+1]=t.y; out[4*k+2]=t.z; out[4*k+3]=t.w;
    }
  }
}
__device__ __forceinline__ void st16(void* p, size_t base, bool isbf, const float* in){
  if(isbf){
    uint16_t* pp=(uint16_t*)p+base;
    uint32_t w[8];
    #pragma unroll
    for(int k=0;k<8;++k) w[k]=(uint32_t)rb16(in[2*k]) | ((uint32_t)rb16(in[2*k+1])<<16);
    *(uint4*)pp     = make_uint4(w[0],w[1],w[2],w[3]);
    *(uint4*)(pp+8) = make_uint4(w[4],w[5],w[6],w[7]);
  } else {
    float* pp=(float*)p+base;
    ((float4*)pp)[0]=make_float4(in[0],in[1],in[2],in[3]);
    ((float4*)pp)[1]=make_float4(in[4],in[5],in[6],in[7]);
    ((float4*)pp)[2]=make_float4(in[8],in[9],in[10],in[11]);
    ((float4*)pp)[3]=make_float4(in[12],in[13],in[14],in[15]);
  }
}

__global__ __launch_bounds__(256) void leapfrog(
    const void* __restrict__ xg, const void* __restrict__ vg,
    const void* __restrict__ fg, const void* __restrict__ Ug,
    const void* __restrict__ Wg, const void* __restrict__ Wfg,
    const void* __restrict__ bg, const int* __restrict__ stepsp,
    void* __restrict__ outp, int n_rows, int n_tiles)
{
  __shared__ float sU [16*SU];     // U[r][d]   at r*SU+d          (4352 B)
  __shared__ float sWr[64*SWR];    // W^T[d][r] at d*SWR+r         (5376 B)
  __shared__ float sWt[128*64];    // Wf^T[j][d] at j*64+d         (32768 B)
  __shared__ float sb [64];        //                              (256 B)
  __shared__ float sFeat[4][16*FST]; // per-wave window buffer     (8704 B)
                                   // total 51456 B

  const int tid=threadIdx.x, lane=tid&63, wid=tid>>6;
  const int q=lane>>4, c=lane&15;
  float* feat=&sFeat[wid][0];

  // ---- runtime dtype detection on U ----
  bool isbf;
  {
    const uint16_t* u=(const uint16_t*)Ug; int cnt=0;
    #pragma unroll
    for(int i=0;i<32;++i){ float t=fabsf(bf1(u[2*i])); cnt += ((t==0.f)||(t>1e-6f&&t<100.f)) ? 1:0; }
    isbf = (cnt>=24);
  }
  int steps = stepsp[0]; steps = steps<0 ? 0 : (steps>16 ? 16 : steps);

  // ---- stage weights as f32 in LDS ----
  for(int i=tid;i<1024;i+=256){ sU[(i>>6)*SU+(i&63)] = ldw(Ug,i,isbf); }
  for(int i=tid;i<1024;i+=256){ int r=i>>6,d=i&63; sWr[d*SWR+r] = ldw(Wg,i,isbf); }
  for(int i=tid;i<8192;i+=256){ int d=i>>7,j=i&127; sWt[j*64+d] = ldw(Wfg,i,isbf); }
  if(tid<64) sb[tid]=ldw(bg,tid,isbf);
  __syncthreads();

  const int tile = blockIdx.x*4 + wid;
  if(tile >= n_tiles) return;

  const size_t base=(size_t)(tile*16+c)*64 + 16*q;

  float vs[16],fs[16],mu[16],vh[16],gm[16],xin[16];
  double x64[16];
  ld16(xg,base,isbf,xin);
  ld16(vg,base,isbf,vs);
  ld16(fg,base,isbf,fs);
  #pragma unroll
  for(int i=0;i<16;++i) x64[i]=(double)xin[i];

  // gamma = ((v @ U^T)^2) @ W, for this thread's 16 dims (verified, unchanged
  // except SWR 20->21 staging stride)
  auto christoffel=[&](const float* vv, float* g){
    float a2[16];
    #pragma unroll
    for(int r=0;r<16;++r){
      const float4* up=(const float4*)&sU[r*SU+16*q];
      float4 u0=up[0],u1=up[1],u2=up[2],u3=up[3];
      float t;
      t =       u0.x*vv[0];      t=fmaf(u0.y,vv[1],t);  t=fmaf(u0.z,vv[2],t);  t=fmaf(u0.w,vv[3],t);
      t=fmaf(u1.x,vv[4],t);  t=fmaf(u1.y,vv[5],t);  t=fmaf(u1.z,vv[6],t);  t=fmaf(u1.w,vv[7],t);
      t=fmaf(u2.x,vv[8],t);  t=fmaf(u2.y,vv[9],t);  t=fmaf(u2.z,vv[10],t); t=fmaf(u2.w,vv[11],t);
      t=fmaf(u3.x,vv[12],t); t=fmaf(u3.y,vv[13],t); t=fmaf(u3.z,vv[14],t); t=fmaf(u3.w,vv[15],t);
      t += __shfl_xor(t,16);
      t += __shfl_xor(t,32);
      a2[r]=t*t;
    }
    #pragma unroll
    for(int i=0;i<16;++i){
      const float4* wp=(const float4*)&sWr[(16*q+i)*SWR];
      float4 w0=wp[0],w1=wp[1],w2=wp[2],w3=wp[3];
      float t;
      t =       a2[0]*w0.x;      t=fmaf(a2[1],w0.y,t);  t=fmaf(a2[2],w0.z,t);  t=fmaf(a2[3],w0.w,t);
      t=fmaf(a2[4],w1.x,t);  t=fmaf(a2[5],w1.y,t);  t=fmaf(a2[6],w1.z,t);  t=fmaf(a2[7],w1.w,t);
      t=fmaf(a2[8],w2.x,t);  t=fmaf(a2[9],w2.y,t);  t=fmaf(a2[10],w2.z,t); t=fmaf(a2[11],w2.w,t);
      t=fmaf(a2[12],w3.x,t); t=fmaf(a2[13],w3.y,t); t=fmaf(a2[14],w3.z,t); t=fmaf(a2[15],w3.w,t);
      g[i]=t;
    }
  };

  // mu = FRIC*sigmoid([sin x, cos x] @ Wf^T + b) — windowed feature exchange.
  // 4 windows of 32 dims: (half=0:sin, half=1:cos) x (w=0: dims 0..31,
  // w=1: dims 32..63). Gate accumulation order is j = 0..127 sequential —
  // bit-identical to the round-5 verified kernel.
  auto friction=[&](float* m){
    float sn[16],cn[16];
    #pragma unroll
    for(int i=0;i<16;++i){ float xf=(float)x64[i]; sn[i]=__sinf(xf); cn[i]=__cosf(xf); }
    float g4[16];   // g4[4*r+dd]: row 4q+r, dim 4c+dd
    {
      float4 b=*(const float4*)&sb[4*c];
      #pragma unroll
      for(int r=0;r<4;++r){ g4[4*r]=b.x; g4[4*r+1]=b.y; g4[4*r+2]=b.z; g4[4*r+3]=b.w; }
    }
    const float* fr0=&feat[(4*q+0)*FST];
    const float* fr1=&feat[(4*q+1)*FST];
    const float* fr2=&feat[(4*q+2)*FST];
    const float* fr3=&feat[(4*q+3)*FST];
    #pragma unroll
    for(int half=0; half<2; ++half){
      const float* src = half ? cn : sn;
      #pragma unroll
      for(int w=0; w<2; ++w){
        // guard: all prior-window reads (whole wave) completed before overwrite
        asm volatile("s_waitcnt lgkmcnt(0)" ::: "memory");
        // publish: lanes whose dims [16q,16q+16) fall in window [32w,32w+32)
        if((q>>1)==w){
          float4* pd=(float4*)&feat[c*FST + 16*(q&1)];
          pd[0]=make_float4(src[ 0],src[ 1],src[ 2],src[ 3]);
          pd[1]=make_float4(src[ 4],src[ 5],src[ 6],src[ 7]);
          pd[2]=make_float4(src[ 8],src[ 9],src[10],src[11]);
          pd[3]=make_float4(src[12],src[13],src[14],src[15]);
        }
        // guard: publishes visible to the whole wave (lgkmcnt is per-wave)
        asm volatile("s_waitcnt lgkmcnt(0)" ::: "memory");
        const int jbase = 64*half + 32*w;
        #pragma unroll 4
        for(int jb=0;jb<8;++jb){
          const int jl=4*jb;
          const int jg=jbase+jl;
          float4 f0=*(const float4*)&fr0[jl];
          float4 f1=*(const float4*)&fr1[jl];
          float4 f2=*(const float4*)&fr2[jl];
          float4 f3=*(const float4*)&fr3[jl];
          float4 w0=*(const float4*)&sWt[(jg+0)*64+4*c];
          float4 w1=*(const float4*)&sWt[(jg+1)*64+4*c];
          float4 w2=*(const float4*)&sWt[(jg+2)*64+4*c];
          float4 w3=*(const float4*)&sWt[(jg+3)*64+4*c];
          // jg+0
          g4[ 0]=fmaf(f0.x,w0.x,g4[ 0]); g4[ 1]=fmaf(f0.x,w0.y,g4[ 1]); g4[ 2]=fmaf(f0.x,w0.z,g4[ 2]); g4[ 3]=fmaf(f0.x,w0.w,g4[ 3]);
          g4[ 4]=fmaf(f1.x,w0.x,g4[ 4]); g4[ 5]=fmaf(f1.x,w0.y,g4[ 5]); g4[ 6]=fmaf(f1.x,w0.z,g4[ 6]); g4[ 7]=fmaf(f1.x,w0.w,g4[ 7]);
          g4[ 8]=fmaf(f2.x,w0.x,g4[ 8]); g4[ 9]=fmaf(f2.x,w0.y,g4[ 9]); g4[10]=fmaf(f2.x,w0.z,g4[10]); g4[11]=fmaf(f2.x,w0.w,g4[11]);
          g4[12]=fmaf(f3.x,w0.x,g4[12]); g4[13]=fmaf(f3.x,w0.y,g4[13]); g4[14]=fmaf(f3.x,w0.z,g4[14]); g4[15]=fmaf(f3.x,w0.w,g4[15]);
          // jg+1
          g4[ 0]=fmaf(f0.y,w1.x,g4[ 0]); g4[ 1]=fmaf(f0.y,w1.y,g4[ 1]); g4[ 2]=fmaf(f0.y,w1.z,g4[ 2]); g4[ 3]=fmaf(f0.y,w1.w,g4[ 3]);
          g4[ 4]=fmaf(f1.y,w1.x,g4[ 4]); g4[ 5]=fmaf(f1.y,w1.y,g4[ 5]); g4[ 6]=fmaf(f1.y,w1.z,g4[ 6]); g4[ 7]=fmaf(f1.y,w1.w,g4[ 7]);
          g4[ 8]=fmaf(f2.y,w1.x,g4[ 8]); g4[ 9]=fmaf(f2.y,w1.y,g4[ 9]); g4[10]=fmaf(f2.y,w1.z,g4[10]); g4[11]=fmaf(f2.y,w1.w,g4[11]);
          g4[12]=fmaf(f3.y,w1.x,g4[12]); g4[13]=fmaf(f3.y,w1.y,g4[13]); g4[14]=fmaf(f3.y,w1.z,g4[14]); g4[15]=fmaf(f3.y,w1.w,g4[15]);
          // jg+2
          g4[ 0]=fmaf(f0.z,w2.x,g4[ 0]); g4[ 1]=fmaf(f0.z,w2.y,g4[ 1]); g4[ 2]=fmaf(f0.z,w2.z,g4[ 2]); g4[ 3]=fmaf(f0.z,w2.w,g4[ 3]);
          g4[ 4]=fmaf(f1.z,w2.x,g4[ 4]); g4[ 5]=fmaf(f1.z,w2.y,g4[ 5]); g4[ 6]=fmaf(f1.z,w2.z,g4[ 6]); g4[ 7]=fmaf(f1.z,w2.w,g4[ 7]);
          g4[ 8]=fmaf(f2.z,w2.x,g4[ 8]); g4[ 9]=fmaf(f2.z,w2.y,g4[ 9]); g4[10]=fmaf(f2.z,w2.z,g4[10]); g4[11]=fmaf(f2.z,w2.w,g4[11]);
          g4[12]=fmaf(f3.z,w2.x,g4[12]); g4[13]=fmaf(f3.z,w2.y,g4[13]); g4[14]=fmaf(f3.z,w2.z,g4[14]); g4[15]=fmaf(f3.z,w2.w,g4[15]);
          // jg+3
          g4[ 0]=fmaf(f0.w,w3.x,g4[ 0]); g4[ 1]=fmaf(f0.w,w3.y,g4[ 1]); g4[ 2]=fmaf(f0.w,w3.z,g4[ 2]); g4[ 3]=fmaf(f0.w,w3.w,g4[ 3]);
          g4[ 4]=fmaf(f1.w,w3.x,g4[ 4]); g4[ 5]=fmaf(f1.w,w3.y,g4[ 5]); g4[ 6]=fmaf(f1.w,w3.z,g4[ 6]); g4[ 7]=fmaf(f1.w,w3.w,g4[ 7]);
          g4[ 8]=fmaf(f2.w,w3.x,g4[ 8]); g4[ 9]=fmaf(f2.w,w3.y,g4[ 9]); g4[10]=fmaf(f2.w,w3.z,g4[10]); g4[11]=fmaf(f2.w,w3.w,g4[11]);
          g4[12]=fmaf(f3.w,w3.x,g4[12]); g4[13]=fmaf(f3.w,w3.y,g4[13]); g4[14]=fmaf(f3.w,w3.z,g4[14]); g4[15]=fmaf(f3.w,w3.w,g4[15]);
        }
      }
    }
    // sigmoid exactly as verified: sg=1/(1+exp(-g)); mu=FRIC*sg
    float muloc[16];
    #pragma unroll
    for(int i=0;i<16;++i) muloc[i]=FRIC*(1.f/(1.f+__expf(-g4[i])));
    // redistribute mu back to integrator layout in 2 dim-half passes
    #pragma unroll
    for(int h=0; h<2; ++h){
      asm volatile("s_waitcnt lgkmcnt(0)" ::: "memory");
      if((c>>3)==h){                      // publisher: dims 4c..4c+3 in half h
        #pragma unroll
        for(int r=0;r<4;++r)
          *(float4*)&feat[(4*q+r)*FST + 4*c - 32*h] =
            make_float4(muloc[4*r],muloc[4*r+1],muloc[4*r+2],muloc[4*r+3]);
      }
      asm volatile("s_waitcnt lgkmcnt(0)" ::: "memory");
      if((q>>1)==h){                      // reader: dims 16q..16q+15 in half h
        #pragma unroll
        for(int k=0;k<4;++k){
          float4 t=*(const float4*)&feat[c*FST + 16*(q&1) + 4*k];
          m[4*k]=t.x; m[4*k+1]=t.y; m[4*k+2]=t.z; m[4*k+3]=t.w;
        }
      }
    }
  };

  friction(mu);                    // mu(x0); carried across half-steps

  for(int s=0;s<steps;++s){
    christoffel(vs,gm);
    {
      #pragma clang fp contract(off)
      #pragma unroll
      for(int i=0;i<16;++i){
        float t  = HDT*(fs[i]-gm[i]);            // np op order
        float num= vs[i]+t;
        float den= (1.f + HDT*mu[i]) + EPS;
        vh[i]= num/den;                          // IEEE division (no fast-math)
        float p  = 0.1f*vh[i];                   // matches np's f32 product
        double xx = x64[i] + (double)p;
        double n  = __builtin_rint(xx*0.15915494309189535);
        x64[i] = __builtin_fma(-6.283185307179586, n, xx);  // exact mod-2pi
      }
    }
    friction(mu);                  // mu_half == next step's mu (bit-identical)
    christoffel(vh,gm);
    {
      #pragma clang fp contract(off)
      #pragma unroll
      for(int i=0;i<16;++i){
        float t  = HDT*(fs[i]-gm[i]);
        float num= vh[i]+t;
        float den= (1.f + HDT*mu[i]) + EPS;
        vs[i]= num/den;
      }
    }
  }

  float xf[16];
  #pragma unroll
  for(int i=0;i<16;++i) xf[i]=(float)x64[i];

  // outputs: (x, v) concatenated; element offset n_rows*64 for v
  const size_t voff=(size_t)n_rows*64;
  if(isbf){
    uint16_t* o=(uint16_t*)outp;
    st16(o,        base, true, xf);
    st16(o+voff,   base, true, vs);
  } else {
    float* o=(float*)outp;
    st16(o,        base, false, xf);
    st16(o+voff,   base, false, vs);
  }
}

extern "C" void kernel_launch(void* const* d_in, const int* in_sizes, int n_in,
                              void* d_out, int out_size, void* d_ws, size_t ws_size,
                              hipStream_t stream) {
  const int n_rows  = in_sizes[0] / 64;
  const int n_tiles = n_rows / 16;
  const int grid    = (n_tiles + 3) / 4;       // 4 waves/block, 1 tile/wave
  leapfrog<<<dim3(grid), dim3(256), 0, stream>>>(
      d_in[0], d_in[1], d_in[2], d_in[3], d_in[4], d_in[5], d_in[6],
      (const int*)d_in[7], d_out, n_rows, n_tiles);
}

// Round 7
// 1260.665 us; speedup vs baseline: 1.5855x; 1.5855x over previous
//
#include <hip/hip_runtime.h>
#include <stdint.h>

// ============================================================================
// LeapfrogIntegrator — round 7: revert round-6 windowing (pure-stall regression:
// 8 lgkmcnt drains/friction serialized the LDS pipeline; VALU-time identical,
// dur 1057->1917). Base = verified 1057us structure, plus:
//   (1) SWR 20 -> 21: christoffel sWr q-groups now 16 banks apart
//       (4-way conflict -> free 2-way).  [predict conflicts 5.6e7 -> ~2e7]
//   (2) 8 waves/block (512 thr, 8 tiles/block): behavioral occupancy probe —
//       if CUs were hosting a single 4-wave block, this doubles waves/SIMD.
//       LDS = 44.8KB weights + 8x8.4KB feat = 112.4KB (<160KB; 128KB precedent).
//
// Integrator layout: lane(q,c) owns row c's dims [16q,16q+16).
// Friction: lane(q,c) accumulates gate for rows 4q..4q+3, dims 4c..4c+3,
// j sequential 0..127; features via per-wave LDS publish (2 lgkmcnt/call).
// Numerics: np op-order fp32 v-updates (contract off, IEEE division),
// fp64 x-chain with exact mod-2pi wrap, friction reuse, sigmoid identical.
// ============================================================================

#define HDT  0.05f
#define EPS  1e-8f
#define FRIC 0.05f

#define SU   68   // U row stride (words)
#define SWT  68   // Wf^T row stride
#define SWR  21   // W^T (dims x ranks) row stride (was 20: 4-way conflict)
#define FSTR 132  // per-wave feature buffer row stride (words)

__device__ __forceinline__ float bf1(uint16_t v){ return __builtin_bit_cast(float,(uint32_t)v<<16); }
__device__ __forceinline__ uint16_t rb16(float f){            // RNE bf16 pack
  uint32_t u=__builtin_bit_cast(uint32_t,f);
  return (uint16_t)((u + 0x7fffu + ((u>>16)&1u))>>16);
}
__device__ __forceinline__ float ldw(const void* p,int i,bool isbf){
  return isbf ? bf1(((const uint16_t*)p)[i]) : ((const float*)p)[i];
}

__device__ __forceinline__ void ld16(const void* p, size_t base, bool isbf, float* out){
  if(isbf){
    const uint16_t* pp=(const uint16_t*)p+base;
    uint4 a=*(const uint4*)pp, b=*(const uint4*)(pp+8);
    uint32_t w[8]={a.x,a.y,a.z,a.w,b.x,b.y,b.z,b.w};
    #pragma unroll
    for(int k=0;k<8;++k){
      out[2*k  ]=__builtin_bit_cast(float,w[k]<<16);
      out[2*k+1]=__builtin_bit_cast(float,w[k]&0xffff0000u);
    }
  } else {
    const float* pp=(const float*)p+base;
    #pragma unroll
    for(int k=0;k<4;++k){
      float4 t=((const float4*)pp)[k];
      out[4*k]=t.x; out[4*k+1]=t.y; out[4*k+2]=t.z; out[4*k+3]=t.w;
    }
  }
}
__device__ __forceinline__ void st16(void* p, size_t base, bool isbf, const float* in){
  if(isbf){
    uint16_t* pp=(uint16_t*)p+base;
    uint32_t w[8];
    #pragma unroll
    for(int k=0;k<8;++k) w[k]=(uint32_t)rb16(in[2*k]) | ((uint32_t)rb16(in[2*k+1])<<16);
    *(uint4*)pp     = make_uint4(w[0],w[1],w[2],w[3]);
    *(uint4*)(pp+8) = make_uint4(w[4],w[5],w[6],w[7]);
  } else {
    float* pp=(float*)p+base;
    ((float4*)pp)[0]=make_float4(in[0],in[1],in[2],in[3]);
    ((float4*)pp)[1]=make_float4(in[4],in[5],in[6],in[7]);
    ((float4*)pp)[2]=make_float4(in[8],in[9],in[10],in[11]);
    ((float4*)pp)[3]=make_float4(in[12],in[13],in[14],in[15]);
  }
}

__global__ __launch_bounds__(512) void leapfrog(
    const void* __restrict__ xg, const void* __restrict__ vg,
    const void* __restrict__ fg, const void* __restrict__ Ug,
    const void* __restrict__ Wg, const void* __restrict__ Wfg,
    const void* __restrict__ bg, const int* __restrict__ stepsp,
    void* __restrict__ outp, int n_rows, int n_tiles)
{
  __shared__ float sU [16*SU];     // U[r][d]   at r*SU+d           (4352 B)
  __shared__ float sWr[64*SWR];    // W^T[d][r] at d*SWR+r          (5376 B)
  __shared__ float sWt[128*SWT];   // Wf^T[j][d] at j*SWT+d         (34816 B)
  __shared__ float sb [64];        //                               (256 B)
  __shared__ float sFeat[8][16*FSTR]; // per-wave feature buffer    (67584 B)
                                   // total 112384 B

  const int tid=threadIdx.x, lane=tid&63, wid=tid>>6;
  const int q=lane>>4, c=lane&15;
  float* feat=&sFeat[wid][0];

  // ---- runtime dtype detection on U ----
  bool isbf;
  {
    const uint16_t* u=(const uint16_t*)Ug; int cnt=0;
    #pragma unroll
    for(int i=0;i<32;++i){ float t=fabsf(bf1(u[2*i])); cnt += ((t==0.f)||(t>1e-6f&&t<100.f)) ? 1:0; }
    isbf = (cnt>=24);
  }
  int steps = stepsp[0]; steps = steps<0 ? 0 : (steps>16 ? 16 : steps);

  // ---- stage weights as f32 in LDS (512 threads) ----
  for(int i=tid;i<1024;i+=512){ sU[(i>>6)*SU+(i&63)] = ldw(Ug,i,isbf); }
  for(int i=tid;i<1024;i+=512){ int r=i>>6,d=i&63; sWr[d*SWR+r] = ldw(Wg,i,isbf); }
  for(int i=tid;i<8192;i+=512){ int d=i>>7,j=i&127; sWt[j*SWT+d] = ldw(Wfg,i,isbf); }
  if(tid<64) sb[tid]=ldw(bg,tid,isbf);
  __syncthreads();

  const int tile = blockIdx.x*8 + wid;
  if(tile >= n_tiles) return;

  const size_t base=(size_t)(tile*16+c)*64 + 16*q;

  float vs[16],fs[16],mu[16],vh[16],gm[16],xin[16];
  double x64[16];
  ld16(xg,base,isbf,xin);
  ld16(vg,base,isbf,vs);
  ld16(fg,base,isbf,fs);
  #pragma unroll
  for(int i=0;i<16;++i) x64[i]=(double)xin[i];

  // gamma = ((v @ U^T)^2) @ W, for this thread's 16 dims
  auto christoffel=[&](const float* vv, float* g){
    float a2[16];
    #pragma unroll
    for(int r=0;r<16;++r){
      const float4* up=(const float4*)&sU[r*SU+16*q];
      float4 u0=up[0],u1=up[1],u2=up[2],u3=up[3];
      float t;
      t =       u0.x*vv[0];      t=fmaf(u0.y,vv[1],t);  t=fmaf(u0.z,vv[2],t);  t=fmaf(u0.w,vv[3],t);
      t=fmaf(u1.x,vv[4],t);  t=fmaf(u1.y,vv[5],t);  t=fmaf(u1.z,vv[6],t);  t=fmaf(u1.w,vv[7],t);
      t=fmaf(u2.x,vv[8],t);  t=fmaf(u2.y,vv[9],t);  t=fmaf(u2.z,vv[10],t); t=fmaf(u2.w,vv[11],t);
      t=fmaf(u3.x,vv[12],t); t=fmaf(u3.y,vv[13],t); t=fmaf(u3.z,vv[14],t); t=fmaf(u3.w,vv[15],t);
      t += __shfl_xor(t,16);
      t += __shfl_xor(t,32);
      a2[r]=t*t;
    }
    #pragma unroll
    for(int i=0;i<16;++i){
      const float4* wp=(const float4*)&sWr[(16*q+i)*SWR];
      float4 w0=wp[0],w1=wp[1],w2=wp[2],w3=wp[3];
      float t;
      t =       a2[0]*w0.x;      t=fmaf(a2[1],w0.y,t);  t=fmaf(a2[2],w0.z,t);  t=fmaf(a2[3],w0.w,t);
      t=fmaf(a2[4],w1.x,t);  t=fmaf(a2[5],w1.y,t);  t=fmaf(a2[6],w1.z,t);  t=fmaf(a2[7],w1.w,t);
      t=fmaf(a2[8],w2.x,t);  t=fmaf(a2[9],w2.y,t);  t=fmaf(a2[10],w2.z,t); t=fmaf(a2[11],w2.w,t);
      t=fmaf(a2[12],w3.x,t); t=fmaf(a2[13],w3.y,t); t=fmaf(a2[14],w3.z,t); t=fmaf(a2[15],w3.w,t);
      g[i]=t;
    }
  };

  // mu = FRIC*sigmoid([sin x, cos x] @ Wf^T + b) — verified 1057us structure.
  // Phase 1: owner lane publishes sin/cos of its 16 dims to feat[row][j].
  // Phase 2: lane (q,c) accumulates gate for rows 4q+r (r=0..3), dims
  //          4c..4c+3, sequentially over j=0..127 (reference order).
  // Phase 3: sigmoid, publish mu, read back in integrator layout.
  // Only 2 lgkmcnt drains per call (wave-synchronous, no barriers).
  auto friction=[&](float* m){
    {
      float sn[16],cn[16];
      #pragma unroll
      for(int i=0;i<16;++i){ float xf=(float)x64[i]; sn[i]=__sinf(xf); cn[i]=__cosf(xf); }
      float4* ps=(float4*)&feat[c*FSTR+16*q];
      float4* pc=(float4*)&feat[c*FSTR+64+16*q];
      #pragma unroll
      for(int k=0;k<4;++k){
        ps[k]=make_float4(sn[4*k],sn[4*k+1],sn[4*k+2],sn[4*k+3]);
        pc[k]=make_float4(cn[4*k],cn[4*k+1],cn[4*k+2],cn[4*k+3]);
      }
    }
    asm volatile("s_waitcnt lgkmcnt(0)" ::: "memory");

    float g4[16];   // g4[4*r+dd]: row 4q+r, dim 4c+dd
    {
      float4 b=*(const float4*)&sb[4*c];
      #pragma unroll
      for(int r=0;r<4;++r){ g4[4*r]=b.x; g4[4*r+1]=b.y; g4[4*r+2]=b.z; g4[4*r+3]=b.w; }
    }
    const float* fr0=&feat[(4*q+0)*FSTR];
    const float* fr1=&feat[(4*q+1)*FSTR];
    const float* fr2=&feat[(4*q+2)*FSTR];
    const float* fr3=&feat[(4*q+3)*FSTR];
    #pragma unroll 4
    for(int jb=0;jb<32;++jb){
      const int j0=4*jb;
      float4 f0=*(const float4*)&fr0[j0];
      float4 f1=*(const float4*)&fr1[j0];
      float4 f2=*(const float4*)&fr2[j0];
      float4 f3=*(const float4*)&fr3[j0];
      float4 w0=*(const float4*)&sWt[(j0+0)*SWT+4*c];
      float4 w1=*(const float4*)&sWt[(j0+1)*SWT+4*c];
      float4 w2=*(const float4*)&sWt[(j0+2)*SWT+4*c];
      float4 w3=*(const float4*)&sWt[(j0+3)*SWT+4*c];
      // j0+0
      g4[ 0]=fmaf(f0.x,w0.x,g4[ 0]); g4[ 1]=fmaf(f0.x,w0.y,g4[ 1]); g4[ 2]=fmaf(f0.x,w0.z,g4[ 2]); g4[ 3]=fmaf(f0.x,w0.w,g4[ 3]);
      g4[ 4]=fmaf(f1.x,w0.x,g4[ 4]); g4[ 5]=fmaf(f1.x,w0.y,g4[ 5]); g4[ 6]=fmaf(f1.x,w0.z,g4[ 6]); g4[ 7]=fmaf(f1.x,w0.w,g4[ 7]);
      g4[ 8]=fmaf(f2.x,w0.x,g4[ 8]); g4[ 9]=fmaf(f2.x,w0.y,g4[ 9]); g4[10]=fmaf(f2.x,w0.z,g4[10]); g4[11]=fmaf(f2.x,w0.w,g4[11]);
      g4[12]=fmaf(f3.x,w0.x,g4[12]); g4[13]=fmaf(f3.x,w0.y,g4[13]); g4[14]=fmaf(f3.x,w0.z,g4[14]); g4[15]=fmaf(f3.x,w0.w,g4[15]);
      // j0+1
      g4[ 0]=fmaf(f0.y,w1.x,g4[ 0]); g4[ 1]=fmaf(f0.y,w1.y,g4[ 1]); g4[ 2]=fmaf(f0.y,w1.z,g4[ 2]); g4[ 3]=fmaf(f0.y,w1.w,g4[ 3]);
      g4[ 4]=fmaf(f1.y,w1.x,g4[ 4]); g4[ 5]=fmaf(f1.y,w1.y,g4[ 5]); g4[ 6]=fmaf(f1.y,w1.z,g4[ 6]); g4[ 7]=fmaf(f1.y,w1.w,g4[ 7]);
      g4[ 8]=fmaf(f2.y,w1.x,g4[ 8]); g4[ 9]=fmaf(f2.y,w1.y,g4[ 9]); g4[10]=fmaf(f2.y,w1.z,g4[10]); g4[11]=fmaf(f2.y,w1.w,g4[11]);
      g4[12]=fmaf(f3.y,w1.x,g4[12]); g4[13]=fmaf(f3.y,w1.y,g4[13]); g4[14]=fmaf(f3.y,w1.z,g4[14]); g4[15]=fmaf(f3.y,w1.w,g4[15]);
      // j0+2
      g4[ 0]=fmaf(f0.z,w2.x,g4[ 0]); g4[ 1]=fmaf(f0.z,w2.y,g4[ 1]); g4[ 2]=fmaf(f0.z,w2.z,g4[ 2]); g4[ 3]=fmaf(f0.z,w2.w,g4[ 3]);
      g4[ 4]=fmaf(f1.z,w2.x,g4[ 4]); g4[ 5]=fmaf(f1.z,w2.y,g4[ 5]); g4[ 6]=fmaf(f1.z,w2.z,g4[ 6]); g4[ 7]=fmaf(f1.z,w2.w,g4[ 7]);
      g4[ 8]=fmaf(f2.z,w2.x,g4[ 8]); g4[ 9]=fmaf(f2.z,w2.y,g4[ 9]); g4[10]=fmaf(f2.z,w2.z,g4[10]); g4[11]=fmaf(f2.z,w2.w,g4[11]);
      g4[12]=fmaf(f3.z,w2.x,g4[12]); g4[13]=fmaf(f3.z,w2.y,g4[13]); g4[14]=fmaf(f3.z,w2.z,g4[14]); g4[15]=fmaf(f3.z,w2.w,g4[15]);
      // j0+3
      g4[ 0]=fmaf(f0.w,w3.x,g4[ 0]); g4[ 1]=fmaf(f0.w,w3.y,g4[ 1]); g4[ 2]=fmaf(f0.w,w3.z,g4[ 2]); g4[ 3]=fmaf(f0.w,w3.w,g4[ 3]);
      g4[ 4]=fmaf(f1.w,w3.x,g4[ 4]); g4[ 5]=fmaf(f1.w,w3.y,g4[ 5]); g4[ 6]=fmaf(f1.w,w3.z,g4[ 6]); g4[ 7]=fmaf(f1.w,w3.w,g4[ 7]);
      g4[ 8]=fmaf(f2.w,w3.x,g4[ 8]); g4[ 9]=fmaf(f2.w,w3.y,g4[ 9]); g4[10]=fmaf(f2.w,w3.z,g4[10]); g4[11]=fmaf(f2.w,w3.w,g4[11]);
      g4[12]=fmaf(f3.w,w3.x,g4[12]); g4[13]=fmaf(f3.w,w3.y,g4[13]); g4[14]=fmaf(f3.w,w3.z,g4[14]); g4[15]=fmaf(f3.w,w3.w,g4[15]);
    }
    // sigmoid exactly as verified kernel: sg=1/(1+exp(-g)); mu=FRIC*sg
    #pragma unroll
    for(int r=0;r<4;++r){
      float s0=1.f/(1.f+__expf(-g4[4*r+0]));
      float s1=1.f/(1.f+__expf(-g4[4*r+1]));
      float s2=1.f/(1.f+__expf(-g4[4*r+2]));
      float s3=1.f/(1.f+__expf(-g4[4*r+3]));
      *(float4*)&feat[(4*q+r)*FSTR+4*c]=make_float4(FRIC*s0,FRIC*s1,FRIC*s2,FRIC*s3);
    }
    asm volatile("s_waitcnt lgkmcnt(0)" ::: "memory");
    #pragma unroll
    for(int k=0;k<4;++k){
      float4 t=*(const float4*)&feat[c*FSTR+16*q+4*k];
      m[4*k]=t.x; m[4*k+1]=t.y; m[4*k+2]=t.z; m[4*k+3]=t.w;
    }
  };

  friction(mu);                    // mu(x0); carried across half-steps

  for(int s=0;s<steps;++s){
    christoffel(vs,gm);
    {
      #pragma clang fp contract(off)
      #pragma unroll
      for(int i=0;i<16;++i){
        float t  = HDT*(fs[i]-gm[i]);            // np op order
        float num= vs[i]+t;
        float den= (1.f + HDT*mu[i]) + EPS;
        vh[i]= num/den;                          // IEEE division (no fast-math)
        float p  = 0.1f*vh[i];                   // matches np's f32 product
        double xx = x64[i] + (double)p;
        double n  = __builtin_rint(xx*0.15915494309189535);
        x64[i] = __builtin_fma(-6.283185307179586, n, xx);  // exact mod-2pi
      }
    }
    friction(mu);                  // mu_half == next step's mu (bit-identical)
    christoffel(vh,gm);
    {
      #pragma clang fp contract(off)
      #pragma unroll
      for(int i=0;i<16;++i){
        float t  = HDT*(fs[i]-gm[i]);
        float num= vh[i]+t;
        float den= (1.f + HDT*mu[i]) + EPS;
        vs[i]= num/den;
      }
    }
  }

  float xf[16];
  #pragma unroll
  for(int i=0;i<16;++i) xf[i]=(float)x64[i];

  // outputs: (x, v) concatenated; element offset n_rows*64 for v
  const size_t voff=(size_t)n_rows*64;
  if(isbf){
    uint16_t* o=(uint16_t*)outp;
    st16(o,        base, true, xf);
    st16(o+voff,   base, true, vs);
  } else {
    float* o=(float*)outp;
    st16(o,        base, false, xf);
    st16(o+voff,   base, false, vs);
  }
}

extern "C" void kernel_launch(void* const* d_in, const int* in_sizes, int n_in,
                              void* d_out, int out_size, void* d_ws, size_t ws_size,
                              hipStream_t stream) {
  const int n_rows  = in_sizes[0] / 64;
  const int n_tiles = n_rows / 16;
  const int grid    = (n_tiles + 7) / 8;       // 8 waves/block, 1 tile/wave
  leapfrog<<<dim3(grid), dim3(512), 0, stream>>>(
      d_in[0], d_in[1], d_in[2], d_in[3], d_in[4], d_in[5], d_in[6],
      (const int*)d_in[7], d_out, n_rows, n_tiles);
}

// Round 10
// 1242.403 us; speedup vs baseline: 1.6088x; 1.0147x over previous
//
#include <hip/hip_runtime.h>
#include <stdint.h>

// ============================================================================
// LeapfrogIntegrator — round 8: friction gate GEMM moved to MFMA (bf16),
// Wf held in REGISTERS as B-fragments (loaded once; LDS weight traffic for
// friction eliminated). Diagnosis: per-CU LDS pipe saturated (R4/R5/R7:
// VALU busy-time conserved ~450us while occupancy x1.8 and conflicts /19
// changed nothing). DS instrs/lane: 2665 -> ~1450.
//
//   * gate[16rows x 64dims] = feat[16x128] @ WfT[128x64] via 16x
//     mfma_f32_16x16x32_bf16 per call (4 N-tiles x 4 K-blocks), f32 accum,
//     bias-initialized. Wf bf16 B-frags: 64 VGPR/lane, loaded once.
//   * features published per call as bf16 into A-frag-native LDS layout
//     featb[B=j/8][row] (16B cells; 2-way banks only); 4 writes + 4 reads.
//   * mu computed from MFMA C-layout (row=4g+r, col=16t+n), sigmoid fp32,
//     redistributed via small LDS buffer (16 b32 w + 4 b128 r).
//   * christoffel UNCHANGED fp32 (bf16 there would cost 10x more error);
//     SWR=21 conflict fix kept (19x conflict drop measured).
//   * x stored f32 between steps (wrap still computed in f64, exact mod-2pi;
//     reference itself carries f32 x) — frees 16 VGPRs.
//   * numerics elsewhere identical: np op-order fp32 v-updates (contract
//     off, IEEE div), friction reuse (mu_half == next mu).
// ============================================================================

#define HDT  0.05f
#define EPS  1e-8f
#define FRIC 0.05f

#define SU   68   // U row stride (words)
#define SWR  21   // W^T (dims x ranks) row stride
#define SMU  68   // mu exchange row stride (words)

typedef short  bf16x8 __attribute__((ext_vector_type(8)));
typedef float  f32x4  __attribute__((ext_vector_type(4)));

__device__ __forceinline__ float bf1(uint16_t v){ return __builtin_bit_cast(float,(uint32_t)v<<16); }
__device__ __forceinline__ uint16_t rb16(float f){            // RNE bf16 pack
  uint32_t u=__builtin_bit_cast(uint32_t,f);
  return (uint16_t)((u + 0x7fffu + ((u>>16)&1u))>>16);
}
__device__ __forceinline__ float ldw(const void* p,int i,bool isbf){
  return isbf ? bf1(((const uint16_t*)p)[i]) : ((const float*)p)[i];
}

__device__ __forceinline__ void ld16(const void* p, size_t base, bool isbf, float* out){
  if(isbf){
    const uint16_t* pp=(const uint16_t*)p+base;
    uint4 a=*(const uint4*)pp, b=*(const uint4*)(pp+8);
    uint32_t w[8]={a.x,a.y,a.z,a.w,b.x,b.y,b.z,b.w};
    #pragma unroll
    for(int k=0;k<8;++k){
      out[2*k  ]=__builtin_bit_cast(float,w[k]<<16);
      out[2*k+1]=__builtin_bit_cast(float,w[k]&0xffff0000u);
    }
  } else {
    const float* pp=(const float*)p+base;
    #pragma unroll
    for(int k=0;k<4;++k){
      float4 t=((const float4*)pp)[k];
      out[4*k]=t.x; out[4*k+1]=t.y; out[4*k+2]=t.z; out[4*k+3]=t.w;
    }
  }
}
__device__ __forceinline__ void st16(void* p, size_t base, bool isbf, const float* in){
  if(isbf){
    uint16_t* pp=(uint16_t*)p+base;
    uint32_t w[8];
    #pragma unroll
    for(int k=0;k<8;++k) w[k]=(uint32_t)rb16(in[2*k]) | ((uint32_t)rb16(in[2*k+1])<<16);
    *(uint4*)pp     = make_uint4(w[0],w[1],w[2],w[3]);
    *(uint4*)(pp+8) = make_uint4(w[4],w[5],w[6],w[7]);
  } else {
    float* pp=(float*)p+base;
    ((float4*)pp)[0]=make_float4(in[0],in[1],in[2],in[3]);
    ((float4*)pp)[1]=make_float4(in[4],in[5],in[6],in[7]);
    ((float4*)pp)[2]=make_float4(in[8],in[9],in[10],in[11]);
    ((float4*)pp)[3]=make_float4(in[12],in[13],in[14],in[15]);
  }
}

__global__ __launch_bounds__(256) void leapfrog(
    const void* __restrict__ xg, const void* __restrict__ vg,
    const void* __restrict__ fg, const void* __restrict__ Ug,
    const void* __restrict__ Wg, const void* __restrict__ Wfg,
    const void* __restrict__ bg, const int* __restrict__ stepsp,
    void* __restrict__ outp, int n_rows, int n_tiles)
{
  __shared__ float    sU [16*SU];        // U[r][d]   at r*SU+d       (4352 B)
  __shared__ float    sWr[64*SWR];       // W^T[d][r] at d*SWR+r      (5376 B)
  __shared__ float    sb [64];           //                           (256 B)
  __shared__ uint16_t sFeat[4][16*16*8]; // [wave][jblock B][row][8]  (16384 B)
  __shared__ float    sMu [4][16*SMU];   // [wave][row][dim+pad]      (17408 B)
                                         // total ~43.8 KB

  const int tid=threadIdx.x, lane=tid&63, wid=tid>>6;
  const int q=lane>>4, c=lane&15;        // integrator coords: row c, dims 16q..
  const int gB=lane>>4, nB=lane&15;      // MFMA coords: k-group g, col/row n

  // ---- runtime dtype detection on U ----
  bool isbf;
  {
    const uint16_t* u=(const uint16_t*)Ug; int cnt=0;
    #pragma unroll
    for(int i=0;i<32;++i){ float t=fabsf(bf1(u[2*i])); cnt += ((t==0.f)||(t>1e-6f&&t<100.f)) ? 1:0; }
    isbf = (cnt>=24);
  }
  int steps = stepsp[0]; steps = steps<0 ? 0 : (steps>16 ? 16 : steps);

  // ---- stage christoffel weights + bias in LDS ----
  for(int i=tid;i<1024;i+=256){ sU[(i>>6)*SU+(i&63)] = ldw(Ug,i,isbf); }
  for(int i=tid;i<1024;i+=256){ int r=i>>6,d=i&63; sWr[d*SWR+r] = ldw(Wg,i,isbf); }
  if(tid<64) sb[tid]=ldw(bg,tid,isbf);
  __syncthreads();

  const int tile = blockIdx.x*4 + wid;
  if(tile >= n_tiles) return;

  // ---- Wf B-fragments in registers (loaded once, reused all 5 calls) ----
  // frag(t,kb): lane(g,n) holds WfT[32kb+8g+e][16t+n] = Wf[16t+n][32kb+8g+e]
  bf16x8 wf[4][4];
  #pragma unroll
  for(int t=0;t<4;++t){
    #pragma unroll
    for(int kb=0;kb<4;++kb){
      const size_t e0=(size_t)(16*t+nB)*128 + 32*kb + 8*gB;
      if(isbf){
        uint4 r=*(const uint4*)((const uint16_t*)Wfg + e0);   // raw bf16 passthrough
        wf[t][kb]=__builtin_bit_cast(bf16x8,r);
      } else {
        const float* p=(const float*)Wfg + e0;
        float4 A=((const float4*)p)[0], B=((const float4*)p)[1];
        uint32_t w0=(uint32_t)rb16(A.x)|((uint32_t)rb16(A.y)<<16);
        uint32_t w1=(uint32_t)rb16(A.z)|((uint32_t)rb16(A.w)<<16);
        uint32_t w2=(uint32_t)rb16(B.x)|((uint32_t)rb16(B.y)<<16);
        uint32_t w3=(uint32_t)rb16(B.z)|((uint32_t)rb16(B.w)<<16);
        wf[t][kb]=__builtin_bit_cast(bf16x8,make_uint4(w0,w1,w2,w3));
      }
    }
  }
  float bias[4];
  #pragma unroll
  for(int t=0;t<4;++t) bias[t]=sb[16*t+nB];

  uint16_t* featw=&sFeat[wid][0];
  float*    muw  =&sMu[wid][0];

  const size_t base=(size_t)(tile*16+c)*64 + 16*q;

  float vs[16],fs[16],mu[16],vh[16],gm[16],xs[16];
  ld16(xg,base,isbf,xs);
  ld16(vg,base,isbf,vs);
  ld16(fg,base,isbf,fs);

  // gamma = ((v @ U^T)^2) @ W, fp32, unchanged (verified)
  auto christoffel=[&](const float* vv, float* g){
    float a2[16];
    #pragma unroll
    for(int r=0;r<16;++r){
      const float4* up=(const float4*)&sU[r*SU+16*q];
      float4 u0=up[0],u1=up[1],u2=up[2],u3=up[3];
      float t;
      t =       u0.x*vv[0];      t=fmaf(u0.y,vv[1],t);  t=fmaf(u0.z,vv[2],t);  t=fmaf(u0.w,vv[3],t);
      t=fmaf(u1.x,vv[4],t);  t=fmaf(u1.y,vv[5],t);  t=fmaf(u1.z,vv[6],t);  t=fmaf(u1.w,vv[7],t);
      t=fmaf(u2.x,vv[8],t);  t=fmaf(u2.y,vv[9],t);  t=fmaf(u2.z,vv[10],t); t=fmaf(u2.w,vv[11],t);
      t=fmaf(u3.x,vv[12],t); t=fmaf(u3.y,vv[13],t); t=fmaf(u3.z,vv[14],t); t=fmaf(u3.w,vv[15],t);
      t += __shfl_xor(t,16);
      t += __shfl_xor(t,32);
      a2[r]=t*t;
    }
    #pragma unroll
    for(int i=0;i<16;++i){
      const float4* wp=(const float4*)&sWr[(16*q+i)*SWR];
      float4 w0=wp[0],w1=wp[1],w2=wp[2],w3=wp[3];
      float t;
      t =       a2[0]*w0.x;      t=fmaf(a2[1],w0.y,t);  t=fmaf(a2[2],w0.z,t);  t=fmaf(a2[3],w0.w,t);
      t=fmaf(a2[4],w1.x,t);  t=fmaf(a2[5],w1.y,t);  t=fmaf(a2[6],w1.z,t);  t=fmaf(a2[7],w1.w,t);
      t=fmaf(a2[8],w2.x,t);  t=fmaf(a2[9],w2.y,t);  t=fmaf(a2[10],w2.z,t); t=fmaf(a2[11],w2.w,t);
      t=fmaf(a2[12],w3.x,t); t=fmaf(a2[13],w3.y,t); t=fmaf(a2[14],w3.z,t); t=fmaf(a2[15],w3.w,t);
      g[i]=t;
    }
  };

  // mu = FRIC*sigmoid([sin x, cos x] @ Wf^T + b) via MFMA.
  // Publish: owner lane(q,c) writes bf16 sin -> blocks B=2q,2q+1 row c;
  //          cos -> blocks B=8+2q,9+2q row c.   (block B holds j=8B..8B+8)
  // A-frag(kb): lane(g,n) reads block 4kb+g, row n (16B, 2-way banks).
  // C: lane(g,n) reg r = gate[row 4g+r][col 16t+n].
  auto friction=[&](float* m){
    {
      float sn[16],cn[16];
      #pragma unroll
      for(int i=0;i<16;++i){ sn[i]=__sinf(xs[i]); cn[i]=__cosf(xs[i]); }
      uint32_t ps[8],pc[8];
      #pragma unroll
      for(int k=0;k<8;++k){
        ps[k]=(uint32_t)rb16(sn[2*k])|((uint32_t)rb16(sn[2*k+1])<<16);
        pc[k]=(uint32_t)rb16(cn[2*k])|((uint32_t)rb16(cn[2*k+1])<<16);
      }
      *(uint4*)&featw[(((2*q  )*16)+c)*8]=make_uint4(ps[0],ps[1],ps[2],ps[3]);
      *(uint4*)&featw[(((2*q+1)*16)+c)*8]=make_uint4(ps[4],ps[5],ps[6],ps[7]);
      *(uint4*)&featw[(((8+2*q)*16)+c)*8]=make_uint4(pc[0],pc[1],pc[2],pc[3]);
      *(uint4*)&featw[(((9+2*q)*16)+c)*8]=make_uint4(pc[4],pc[5],pc[6],pc[7]);
    }
    asm volatile("s_waitcnt lgkmcnt(0)" ::: "memory");
    f32x4 a0={bias[0],bias[0],bias[0],bias[0]};
    f32x4 a1={bias[1],bias[1],bias[1],bias[1]};
    f32x4 a2={bias[2],bias[2],bias[2],bias[2]};
    f32x4 a3={bias[3],bias[3],bias[3],bias[3]};
    #pragma unroll
    for(int kb=0;kb<4;++kb){
      bf16x8 af=__builtin_bit_cast(bf16x8,
                 *(const uint4*)&featw[(((4*kb+gB)*16)+nB)*8]);
      a0=__builtin_amdgcn_mfma_f32_16x16x32_bf16(af,wf[0][kb],a0,0,0,0);
      a1=__builtin_amdgcn_mfma_f32_16x16x32_bf16(af,wf[1][kb],a1,0,0,0);
      a2=__builtin_amdgcn_mfma_f32_16x16x32_bf16(af,wf[2][kb],a2,0,0,0);
      a3=__builtin_amdgcn_mfma_f32_16x16x32_bf16(af,wf[3][kb],a3,0,0,0);
    }
    // sigmoid (fp32) + scatter to integrator layout via small LDS buffer
    #pragma unroll
    for(int r=0;r<4;++r){
      muw[(4*gB+r)*SMU +  0 + nB]=FRIC*(1.f/(1.f+__expf(-a0[r])));
      muw[(4*gB+r)*SMU + 16 + nB]=FRIC*(1.f/(1.f+__expf(-a1[r])));
      muw[(4*gB+r)*SMU + 32 + nB]=FRIC*(1.f/(1.f+__expf(-a2[r])));
      muw[(4*gB+r)*SMU + 48 + nB]=FRIC*(1.f/(1.f+__expf(-a3[r])));
    }
    asm volatile("s_waitcnt lgkmcnt(0)" ::: "memory");
    #pragma unroll
    for(int k=0;k<4;++k){
      float4 t=*(const float4*)&muw[c*SMU+16*q+4*k];
      m[4*k]=t.x; m[4*k+1]=t.y; m[4*k+2]=t.z; m[4*k+3]=t.w;
    }
  };

  friction(mu);                    // mu(x0); carried across half-steps

  for(int s=0;s<steps;++s){
    christoffel(vs,gm);
    {
      #pragma clang fp contract(off)
      #pragma unroll
      for(int i=0;i<16;++i){
        float t  = HDT*(fs[i]-gm[i]);            // np op order
        float num= vs[i]+t;
        float den= (1.f + HDT*mu[i]) + EPS;
        vh[i]= num/den;                          // IEEE division (no fast-math)
        float p  = 0.1f*vh[i];                   // matches np's f32 product
        double xx = (double)xs[i] + (double)p;
        double n  = __builtin_rint(xx*0.15915494309189535);
        xs[i] = (float)__builtin_fma(-6.283185307179586, n, xx); // exact mod-2pi
      }
    }
    friction(mu);                  // mu_half == next step's mu (bit-identical)
    christoffel(vh,gm);
    {
      #pragma clang fp contract(off)
      #pragma unroll
      for(int i=0;i<16;++i){
        float t  = HDT*(fs[i]-gm[i]);
        float num= vh[i]+t;
        float den= (1.f + HDT*mu[i]) + EPS;
        vs[i]= num/den;
      }
    }
  }

  // outputs: (x, v) concatenated; element offset n_rows*64 for v
  const size_t voff=(size_t)n_rows*64;
  if(isbf){
    uint16_t* o=(uint16_t*)outp;
    st16(o,        base, true, xs);
    st16(o+voff,   base, true, vs);
  } else {
    float* o=(float*)outp;
    st16(o,        base, false, xs);
    st16(o+voff,   base, false, vs);
  }
}

extern "C" void kernel_launch(void* const* d_in, const int* in_sizes, int n_in,
                              void* d_out, int out_size, void* d_ws, size_t ws_size,
                              hipStream_t stream) {
  const int n_rows  = in_sizes[0] / 64;
  const int n_tiles = n_rows / 16;
  const int grid    = (n_tiles + 3) / 4;       // 4 waves/block, 1 tile/wave
  leapfrog<<<dim3(grid), dim3(256), 0, stream>>>(
      d_in[0], d_in[1], d_in[2], d_in[3], d_in[4], d_in[5], d_in[6],
      (const int*)d_in[7], d_out, n_rows, n_tiles);
}

// Round 11
// 676.418 us; speedup vs baseline: 2.9549x; 1.8367x over previous
//
#include <hip/hip_runtime.h>
#include <stdint.h>

// ============================================================================
// LeapfrogIntegrator — round 11: CODE-SIZE reduction (I$-thrash theory).
// R4/R7/R10 conserved ~1050-1200us across heavy-DS / 2x-wave / MFMA variants
// while VALU 27-43%, DS-issue ~4%, HBM 2.7%, MFMA 0.8% — all pipes idle.
// Old structure: ~8-10k instrs (~80KB) fully unrolled >> I$; per-block time
// matches L2 instruction-fetch rate. This round shrinks code ~5x:
//   * christoffel: rank-LOOP (#pragma unroll 4): per rank r: dot(16 fma,
//     const-indexed vv) -> 2 shfl_xor -> t*t -> g[i]+=t*W[r][i] (16 fma,
//     const-indexed g). No a2[] register array. fmaf(t,w,0)==t*w exactly,
//     ascending-r accumulation => BIT-IDENTICAL to R10's phase2 chain.
//   * W staged [r][d] like U (sW, stride 68) instead of transposed.
//   * everything else VERBATIM from the passing R10 kernel: MFMA friction
//     (Wf reg B-frags), exchanges, v-update numerics, f64 wrap, grid.
// Register arrays are only const-indexed (rule #20): g/vv unrolled inner,
// v-update loops remain fully unrolled.
// ============================================================================

#define HDT  0.05f
#define EPS  1e-8f
#define FRIC 0.05f

#define SU   68   // U row stride (words)
#define SMU  68   // mu exchange row stride (words)

typedef short  bf16x8 __attribute__((ext_vector_type(8)));
typedef float  f32x4  __attribute__((ext_vector_type(4)));

__device__ __forceinline__ float bf1(uint16_t v){ return __builtin_bit_cast(float,(uint32_t)v<<16); }
__device__ __forceinline__ uint16_t rb16(float f){            // RNE bf16 pack
  uint32_t u=__builtin_bit_cast(uint32_t,f);
  return (uint16_t)((u + 0x7fffu + ((u>>16)&1u))>>16);
}
__device__ __forceinline__ float ldw(const void* p,int i,bool isbf){
  return isbf ? bf1(((const uint16_t*)p)[i]) : ((const float*)p)[i];
}

__device__ __forceinline__ void ld16(const void* p, size_t base, bool isbf, float* out){
  if(isbf){
    const uint16_t* pp=(const uint16_t*)p+base;
    uint4 a=*(const uint4*)pp, b=*(const uint4*)(pp+8);
    uint32_t w[8]={a.x,a.y,a.z,a.w,b.x,b.y,b.z,b.w};
    #pragma unroll
    for(int k=0;k<8;++k){
      out[2*k  ]=__builtin_bit_cast(float,w[k]<<16);
      out[2*k+1]=__builtin_bit_cast(float,w[k]&0xffff0000u);
    }
  } else {
    const float* pp=(const float*)p+base;
    #pragma unroll
    for(int k=0;k<4;++k){
      float4 t=((const float4*)pp)[k];
      out[4*k]=t.x; out[4*k+1]=t.y; out[4*k+2]=t.z; out[4*k+3]=t.w;
    }
  }
}
__device__ __forceinline__ void st16(void* p, size_t base, bool isbf, const float* in){
  if(isbf){
    uint16_t* pp=(uint16_t*)p+base;
    uint32_t w[8];
    #pragma unroll
    for(int k=0;k<8;++k) w[k]=(uint32_t)rb16(in[2*k]) | ((uint32_t)rb16(in[2*k+1])<<16);
    *(uint4*)pp     = make_uint4(w[0],w[1],w[2],w[3]);
    *(uint4*)(pp+8) = make_uint4(w[4],w[5],w[6],w[7]);
  } else {
    float* pp=(float*)p+base;
    ((float4*)pp)[0]=make_float4(in[0],in[1],in[2],in[3]);
    ((float4*)pp)[1]=make_float4(in[4],in[5],in[6],in[7]);
    ((float4*)pp)[2]=make_float4(in[8],in[9],in[10],in[11]);
    ((float4*)pp)[3]=make_float4(in[12],in[13],in[14],in[15]);
  }
}

__global__ __launch_bounds__(256) void leapfrog(
    const void* __restrict__ xg, const void* __restrict__ vg,
    const void* __restrict__ fg, const void* __restrict__ Ug,
    const void* __restrict__ Wg, const void* __restrict__ Wfg,
    const void* __restrict__ bg, const int* __restrict__ stepsp,
    void* __restrict__ outp, int n_rows, int n_tiles)
{
  __shared__ float    sU [16*SU];        // U[r][d]   at r*SU+d       (4352 B)
  __shared__ float    sW [16*SU];        // W[r][d]   at r*SU+d       (4352 B)
  __shared__ float    sb [64];           //                           (256 B)
  __shared__ uint16_t sFeat[4][16*16*8]; // [wave][jblock B][row][8]  (16384 B)
  __shared__ float    sMu [4][16*SMU];   // [wave][row][dim+pad]      (17408 B)
                                         // total ~42.8 KB

  const int tid=threadIdx.x, lane=tid&63, wid=tid>>6;
  const int q=lane>>4, c=lane&15;        // integrator coords: row c, dims 16q..
  const int gB=lane>>4, nB=lane&15;      // MFMA coords: k-group g, col/row n

  // ---- runtime dtype detection on U ----
  bool isbf;
  {
    const uint16_t* u=(const uint16_t*)Ug; int cnt=0;
    #pragma unroll 4
    for(int i=0;i<32;++i){ float t=fabsf(bf1(u[2*i])); cnt += ((t==0.f)||(t>1e-6f&&t<100.f)) ? 1:0; }
    isbf = (cnt>=24);
  }
  int steps = stepsp[0]; steps = steps<0 ? 0 : (steps>16 ? 16 : steps);

  // ---- stage christoffel weights + bias in LDS ----
  for(int i=tid;i<1024;i+=256){ sU[(i>>6)*SU+(i&63)] = ldw(Ug,i,isbf); }
  for(int i=tid;i<1024;i+=256){ sW[(i>>6)*SU+(i&63)] = ldw(Wg,i,isbf); }
  if(tid<64) sb[tid]=ldw(bg,tid,isbf);
  __syncthreads();

  const int tile = blockIdx.x*4 + wid;
  if(tile >= n_tiles) return;

  // ---- Wf B-fragments in registers (loaded once, reused all calls) ----
  // frag(t,kb): lane(g,n) holds WfT[32kb+8g+e][16t+n] = Wf[16t+n][32kb+8g+e]
  bf16x8 wf[4][4];
  #pragma unroll
  for(int t=0;t<4;++t){
    #pragma unroll
    for(int kb=0;kb<4;++kb){
      const size_t e0=(size_t)(16*t+nB)*128 + 32*kb + 8*gB;
      if(isbf){
        uint4 r=*(const uint4*)((const uint16_t*)Wfg + e0);   // raw bf16 passthrough
        wf[t][kb]=__builtin_bit_cast(bf16x8,r);
      } else {
        const float* p=(const float*)Wfg + e0;
        float4 A=((const float4*)p)[0], B=((const float4*)p)[1];
        uint32_t w0=(uint32_t)rb16(A.x)|((uint32_t)rb16(A.y)<<16);
        uint32_t w1=(uint32_t)rb16(A.z)|((uint32_t)rb16(A.w)<<16);
        uint32_t w2=(uint32_t)rb16(B.x)|((uint32_t)rb16(B.y)<<16);
        uint32_t w3=(uint32_t)rb16(B.z)|((uint32_t)rb16(B.w)<<16);
        wf[t][kb]=__builtin_bit_cast(bf16x8,make_uint4(w0,w1,w2,w3));
      }
    }
  }
  float bias[4];
  #pragma unroll
  for(int t=0;t<4;++t) bias[t]=sb[16*t+nB];

  uint16_t* featw=&sFeat[wid][0];
  float*    muw  =&sMu[wid][0];

  const size_t base=(size_t)(tile*16+c)*64 + 16*q;

  float vs[16],fs[16],mu[16],vh[16],gm[16],xs[16];
  ld16(xg,base,isbf,xs);
  ld16(vg,base,isbf,vs);
  ld16(fg,base,isbf,fs);

  // gamma = ((v @ U^T)^2) @ W — rank-looped, small code.
  // Per rank r: t = dot(U[r][16q..], vv) wave-reduced over q-groups; t*t;
  // g[i] += t * W[r][16q+i].  fmaf ascending r == R10's phase2 chain exactly.
  auto christoffel=[&](const float* vv, float* g){
    #pragma unroll
    for(int i=0;i<16;++i) g[i]=0.f;
    #pragma unroll 4
    for(int r=0;r<16;++r){
      const float4* up=(const float4*)&sU[r*SU+16*q];
      float4 u0=up[0],u1=up[1],u2=up[2],u3=up[3];
      float t;
      t =       u0.x*vv[0];  t=fmaf(u0.y,vv[1],t);  t=fmaf(u0.z,vv[2],t);  t=fmaf(u0.w,vv[3],t);
      t=fmaf(u1.x,vv[4],t);  t=fmaf(u1.y,vv[5],t);  t=fmaf(u1.z,vv[6],t);  t=fmaf(u1.w,vv[7],t);
      t=fmaf(u2.x,vv[8],t);  t=fmaf(u2.y,vv[9],t);  t=fmaf(u2.z,vv[10],t); t=fmaf(u2.w,vv[11],t);
      t=fmaf(u3.x,vv[12],t); t=fmaf(u3.y,vv[13],t); t=fmaf(u3.z,vv[14],t); t=fmaf(u3.w,vv[15],t);
      t += __shfl_xor(t,16);
      t += __shfl_xor(t,32);
      t = t*t;
      const float4* wp=(const float4*)&sW[r*SU+16*q];
      float4 w0=wp[0],w1=wp[1],w2=wp[2],w3=wp[3];
      g[ 0]=fmaf(t,w0.x,g[ 0]); g[ 1]=fmaf(t,w0.y,g[ 1]); g[ 2]=fmaf(t,w0.z,g[ 2]); g[ 3]=fmaf(t,w0.w,g[ 3]);
      g[ 4]=fmaf(t,w1.x,g[ 4]); g[ 5]=fmaf(t,w1.y,g[ 5]); g[ 6]=fmaf(t,w1.z,g[ 6]); g[ 7]=fmaf(t,w1.w,g[ 7]);
      g[ 8]=fmaf(t,w2.x,g[ 8]); g[ 9]=fmaf(t,w2.y,g[ 9]); g[10]=fmaf(t,w2.z,g[10]); g[11]=fmaf(t,w2.w,g[11]);
      g[12]=fmaf(t,w3.x,g[12]); g[13]=fmaf(t,w3.y,g[13]); g[14]=fmaf(t,w3.z,g[14]); g[15]=fmaf(t,w3.w,g[15]);
    }
  };

  // mu = FRIC*sigmoid([sin x, cos x] @ Wf^T + b) via MFMA — verbatim R10.
  auto friction=[&](float* m){
    {
      float sn[16],cn[16];
      #pragma unroll
      for(int i=0;i<16;++i){ sn[i]=__sinf(xs[i]); cn[i]=__cosf(xs[i]); }
      uint32_t ps[8],pc[8];
      #pragma unroll
      for(int k=0;k<8;++k){
        ps[k]=(uint32_t)rb16(sn[2*k])|((uint32_t)rb16(sn[2*k+1])<<16);
        pc[k]=(uint32_t)rb16(cn[2*k])|((uint32_t)rb16(cn[2*k+1])<<16);
      }
      *(uint4*)&featw[(((2*q  )*16)+c)*8]=make_uint4(ps[0],ps[1],ps[2],ps[3]);
      *(uint4*)&featw[(((2*q+1)*16)+c)*8]=make_uint4(ps[4],ps[5],ps[6],ps[7]);
      *(uint4*)&featw[(((8+2*q)*16)+c)*8]=make_uint4(pc[0],pc[1],pc[2],pc[3]);
      *(uint4*)&featw[(((9+2*q)*16)+c)*8]=make_uint4(pc[4],pc[5],pc[6],pc[7]);
    }
    asm volatile("s_waitcnt lgkmcnt(0)" ::: "memory");
    f32x4 a0={bias[0],bias[0],bias[0],bias[0]};
    f32x4 a1={bias[1],bias[1],bias[1],bias[1]};
    f32x4 a2={bias[2],bias[2],bias[2],bias[2]};
    f32x4 a3={bias[3],bias[3],bias[3],bias[3]};
    #pragma unroll
    for(int kb=0;kb<4;++kb){
      bf16x8 af=__builtin_bit_cast(bf16x8,
                 *(const uint4*)&featw[(((4*kb+gB)*16)+nB)*8]);
      a0=__builtin_amdgcn_mfma_f32_16x16x32_bf16(af,wf[0][kb],a0,0,0,0);
      a1=__builtin_amdgcn_mfma_f32_16x16x32_bf16(af,wf[1][kb],a1,0,0,0);
      a2=__builtin_amdgcn_mfma_f32_16x16x32_bf16(af,wf[2][kb],a2,0,0,0);
      a3=__builtin_amdgcn_mfma_f32_16x16x32_bf16(af,wf[3][kb],a3,0,0,0);
    }
    #pragma unroll
    for(int r=0;r<4;++r){
      muw[(4*gB+r)*SMU +  0 + nB]=FRIC*(1.f/(1.f+__expf(-a0[r])));
      muw[(4*gB+r)*SMU + 16 + nB]=FRIC*(1.f/(1.f+__expf(-a1[r])));
      muw[(4*gB+r)*SMU + 32 + nB]=FRIC*(1.f/(1.f+__expf(-a2[r])));
      muw[(4*gB+r)*SMU + 48 + nB]=FRIC*(1.f/(1.f+__expf(-a3[r])));
    }
    asm volatile("s_waitcnt lgkmcnt(0)" ::: "memory");
    #pragma unroll
    for(int k=0;k<4;++k){
      float4 t=*(const float4*)&muw[c*SMU+16*q+4*k];
      m[4*k]=t.x; m[4*k+1]=t.y; m[4*k+2]=t.z; m[4*k+3]=t.w;
    }
  };

  friction(mu);                    // mu(x0); carried across half-steps

  for(int s=0;s<steps;++s){
    christoffel(vs,gm);
    {
      #pragma clang fp contract(off)
      #pragma unroll
      for(int i=0;i<16;++i){
        float t  = HDT*(fs[i]-gm[i]);            // np op order
        float num= vs[i]+t;
        float den= (1.f + HDT*mu[i]) + EPS;
        vh[i]= num/den;                          // IEEE division (no fast-math)
        float p  = 0.1f*vh[i];                   // matches np's f32 product
        double xx = (double)xs[i] + (double)p;
        double n  = __builtin_rint(xx*0.15915494309189535);
        xs[i] = (float)__builtin_fma(-6.283185307179586, n, xx); // exact mod-2pi
      }
    }
    friction(mu);                  // mu_half == next step's mu (bit-identical)
    christoffel(vh,gm);
    {
      #pragma clang fp contract(off)
      #pragma unroll
      for(int i=0;i<16;++i){
        float t  = HDT*(fs[i]-gm[i]);
        float num= vh[i]+t;
        float den= (1.f + HDT*mu[i]) + EPS;
        vs[i]= num/den;
      }
    }
  }

  // outputs: (x, v) concatenated; element offset n_rows*64 for v
  const size_t voff=(size_t)n_rows*64;
  if(isbf){
    uint16_t* o=(uint16_t*)outp;
    st16(o,        base, true, xs);
    st16(o+voff,   base, true, vs);
  } else {
    float* o=(float*)outp;
    st16(o,        base, false, xs);
    st16(o+voff,   base, false, vs);
  }
}

extern "C" void kernel_launch(void* const* d_in, const int* in_sizes, int n_in,
                              void* d_out, int out_size, void* d_ws, size_t ws_size,
                              hipStream_t stream) {
  const int n_rows  = in_sizes[0] / 64;
  const int n_tiles = n_rows / 16;
  const int grid    = (n_tiles + 3) / 4;       // 4 waves/block, 1 tile/wave
  leapfrog<<<dim3(grid), dim3(256), 0, stream>>>(
      d_in[0], d_in[1], d_in[2], d_in[3], d_in[4], d_in[5], d_in[6],
      (const int*)d_in[7], d_out, n_rows, n_tiles);
}

// Round 13
// 640.176 us; speedup vs baseline: 3.1222x; 1.0566x over previous
//
#include <hip/hip_runtime.h>
#include <stdint.h>

// ============================================================================
// LeapfrogIntegrator — round 12: VALU-divide elimination + LDS union.
// R11 confirmed I$-thrash (1106->528us after 5x code shrink). Now: VALUBusy
// 49.6% (262us busy), occupancy 22.5% (2 blocks/CU, LDS-limited at 43KB).
//   (1) v_rcp_f32 replaces IEEE divide in v-updates (128x) and sigmoid (80x):
//       den in [1.0,1.005] -> rcp error ~1e-7 rel, 300x below bf16 output
//       quantum. Cuts ~2k VALU instr/lane (-30%).
//   (2) sFeat/sMu UNION (uses are sequential + data-dep ordered within each
//       friction call; cross-call order forced by xs->sn->publish dep chain):
//       LDS 43 -> 26.4KB. If LDS was the 2-block limiter -> 4+ blocks/CU.
// Everything else verbatim R11: rank-looped fp32 christoffel (bit-identical
// chain), MFMA bf16 friction gate w/ reg-resident Wf frags, f64 exact wrap,
// np op-order v-updates, friction reuse.
// ============================================================================

#define HDT  0.05f
#define EPS  1e-8f
#define FRIC 0.05f

#define SU   68   // U/W row stride (words)
#define SMU  68   // exchange row stride (words)

typedef short  bf16x8 __attribute__((ext_vector_type(8)));
typedef float  f32x4  __attribute__((ext_vector_type(4)));

__device__ __forceinline__ float bf1(uint16_t v){ return __builtin_bit_cast(float,(uint32_t)v<<16); }
__device__ __forceinline__ uint16_t rb16(float f){            // RNE bf16 pack
  uint32_t u=__builtin_bit_cast(uint32_t,f);
  return (uint16_t)((u + 0x7fffu + ((u>>16)&1u))>>16);
}
__device__ __forceinline__ float ldw(const void* p,int i,bool isbf){
  return isbf ? bf1(((const uint16_t*)p)[i]) : ((const float*)p)[i];
}

__device__ __forceinline__ void ld16(const void* p, size_t base, bool isbf, float* out){
  if(isbf){
    const uint16_t* pp=(const uint16_t*)p+base;
    uint4 a=*(const uint4*)pp, b=*(const uint4*)(pp+8);
    uint32_t w[8]={a.x,a.y,a.z,a.w,b.x,b.y,b.z,b.w};
    #pragma unroll
    for(int k=0;k<8;++k){
      out[2*k  ]=__builtin_bit_cast(float,w[k]<<16);
      out[2*k+1]=__builtin_bit_cast(float,w[k]&0xffff0000u);
    }
  } else {
    const float* pp=(const float*)p+base;
    #pragma unroll
    for(int k=0;k<4;++k){
      float4 t=((const float4*)pp)[k];
      out[4*k]=t.x; out[4*k+1]=t.y; out[4*k+2]=t.z; out[4*k+3]=t.w;
    }
  }
}
__device__ __forceinline__ void st16(void* p, size_t base, bool isbf, const float* in){
  if(isbf){
    uint16_t* pp=(uint16_t*)p+base;
    uint32_t w[8];
    #pragma unroll
    for(int k=0;k<8;++k) w[k]=(uint32_t)rb16(in[2*k]) | ((uint32_t)rb16(in[2*k+1])<<16);
    *(uint4*)pp     = make_uint4(w[0],w[1],w[2],w[3]);
    *(uint4*)(pp+8) = make_uint4(w[4],w[5],w[6],w[7]);
  } else {
    float* pp=(float*)p+base;
    ((float4*)pp)[0]=make_float4(in[0],in[1],in[2],in[3]);
    ((float4*)pp)[1]=make_float4(in[4],in[5],in[6],in[7]);
    ((float4*)pp)[2]=make_float4(in[8],in[9],in[10],in[11]);
    ((float4*)pp)[3]=make_float4(in[12],in[13],in[14],in[15]);
  }
}

__global__ __launch_bounds__(256) void leapfrog(
    const void* __restrict__ xg, const void* __restrict__ vg,
    const void* __restrict__ fg, const void* __restrict__ Ug,
    const void* __restrict__ Wg, const void* __restrict__ Wfg,
    const void* __restrict__ bg, const int* __restrict__ stepsp,
    void* __restrict__ outp, int n_rows, int n_tiles)
{
  __shared__ float    sU [16*SU];   // U[r][d] at r*SU+d            (4352 B)
  __shared__ float    sW [16*SU];   // W[r][d] at r*SU+d            (4352 B)
  __shared__ float    sb [64];      //                              (256 B)
  __shared__ float    sXch[4][16*SMU]; // per-wave exchange UNION   (17408 B)
                                    // features (bf16, 4KB) then mu (f32)
                                    // total ~26.4 KB

  const int tid=threadIdx.x, lane=tid&63, wid=tid>>6;
  const int q=lane>>4, c=lane&15;        // integrator coords: row c, dims 16q..
  const int gB=lane>>4, nB=lane&15;      // MFMA coords: k-group g, col/row n

  // ---- runtime dtype detection on U ----
  bool isbf;
  {
    const uint16_t* u=(const uint16_t*)Ug; int cnt=0;
    #pragma unroll 4
    for(int i=0;i<32;++i){ float t=fabsf(bf1(u[2*i])); cnt += ((t==0.f)||(t>1e-6f&&t<100.f)) ? 1:0; }
    isbf = (cnt>=24);
  }
  int steps = stepsp[0]; steps = steps<0 ? 0 : (steps>16 ? 16 : steps);

  // ---- stage christoffel weights + bias in LDS ----
  for(int i=tid;i<1024;i+=256){ sU[(i>>6)*SU+(i&63)] = ldw(Ug,i,isbf); }
  for(int i=tid;i<1024;i+=256){ sW[(i>>6)*SU+(i&63)] = ldw(Wg,i,isbf); }
  if(tid<64) sb[tid]=ldw(bg,tid,isbf);
  __syncthreads();

  const int tile = blockIdx.x*4 + wid;
  if(tile >= n_tiles) return;

  // ---- Wf B-fragments in registers (loaded once, reused all calls) ----
  // frag(t,kb): lane(g,n) holds WfT[32kb+8g+e][16t+n] = Wf[16t+n][32kb+8g+e]
  bf16x8 wf[4][4];
  #pragma unroll
  for(int t=0;t<4;++t){
    #pragma unroll
    for(int kb=0;kb<4;++kb){
      const size_t e0=(size_t)(16*t+nB)*128 + 32*kb + 8*gB;
      if(isbf){
        uint4 r=*(const uint4*)((const uint16_t*)Wfg + e0);   // raw bf16 passthrough
        wf[t][kb]=__builtin_bit_cast(bf16x8,r);
      } else {
        const float* p=(const float*)Wfg + e0;
        float4 A=((const float4*)p)[0], B=((const float4*)p)[1];
        uint32_t w0=(uint32_t)rb16(A.x)|((uint32_t)rb16(A.y)<<16);
        uint32_t w1=(uint32_t)rb16(A.z)|((uint32_t)rb16(A.w)<<16);
        uint32_t w2=(uint32_t)rb16(B.x)|((uint32_t)rb16(B.y)<<16);
        uint32_t w3=(uint32_t)rb16(B.z)|((uint32_t)rb16(B.w)<<16);
        wf[t][kb]=__builtin_bit_cast(bf16x8,make_uint4(w0,w1,w2,w3));
      }
    }
  }
  float bias[4];
  #pragma unroll
  for(int t=0;t<4;++t) bias[t]=sb[16*t+nB];

  uint16_t* featw=(uint16_t*)&sXch[wid][0];   // 4096 B used of 4352 B/wave
  float*    muw  =&sXch[wid][0];              // same storage, sequential use

  const size_t base=(size_t)(tile*16+c)*64 + 16*q;

  float vs[16],fs[16],mu[16],vh[16],gm[16],xs[16];
  ld16(xg,base,isbf,xs);
  ld16(vg,base,isbf,vs);
  ld16(fg,base,isbf,fs);

  // gamma = ((v @ U^T)^2) @ W — rank-looped (bit-identical chain to R10/R11)
  auto christoffel=[&](const float* vv, float* g){
    #pragma unroll
    for(int i=0;i<16;++i) g[i]=0.f;
    #pragma unroll 4
    for(int r=0;r<16;++r){
      const float4* up=(const float4*)&sU[r*SU+16*q];
      float4 u0=up[0],u1=up[1],u2=up[2],u3=up[3];
      float t;
      t =       u0.x*vv[0];  t=fmaf(u0.y,vv[1],t);  t=fmaf(u0.z,vv[2],t);  t=fmaf(u0.w,vv[3],t);
      t=fmaf(u1.x,vv[4],t);  t=fmaf(u1.y,vv[5],t);  t=fmaf(u1.z,vv[6],t);  t=fmaf(u1.w,vv[7],t);
      t=fmaf(u2.x,vv[8],t);  t=fmaf(u2.y,vv[9],t);  t=fmaf(u2.z,vv[10],t); t=fmaf(u2.w,vv[11],t);
      t=fmaf(u3.x,vv[12],t); t=fmaf(u3.y,vv[13],t); t=fmaf(u3.z,vv[14],t); t=fmaf(u3.w,vv[15],t);
      t += __shfl_xor(t,16);
      t += __shfl_xor(t,32);
      t = t*t;
      const float4* wp=(const float4*)&sW[r*SU+16*q];
      float4 w0=wp[0],w1=wp[1],w2=wp[2],w3=wp[3];
      g[ 0]=fmaf(t,w0.x,g[ 0]); g[ 1]=fmaf(t,w0.y,g[ 1]); g[ 2]=fmaf(t,w0.z,g[ 2]); g[ 3]=fmaf(t,w0.w,g[ 3]);
      g[ 4]=fmaf(t,w1.x,g[ 4]); g[ 5]=fmaf(t,w1.y,g[ 5]); g[ 6]=fmaf(t,w1.z,g[ 6]); g[ 7]=fmaf(t,w1.w,g[ 7]);
      g[ 8]=fmaf(t,w2.x,g[ 8]); g[ 9]=fmaf(t,w2.y,g[ 9]); g[10]=fmaf(t,w2.z,g[10]); g[11]=fmaf(t,w2.w,g[11]);
      g[12]=fmaf(t,w3.x,g[12]); g[13]=fmaf(t,w3.y,g[13]); g[14]=fmaf(t,w3.z,g[14]); g[15]=fmaf(t,w3.w,g[15]);
    }
  };

  // mu = FRIC*sigmoid([sin x, cos x] @ Wf^T + b) via MFMA.
  // Order within call: featw writes -> lgkmcnt -> af reads -> MFMA ->
  // muw writes (dep on MFMA results) -> lgkmcnt -> mu reads. Union-safe:
  // every cross-use is ordered by data dependence or the asm waits.
  auto friction=[&](float* m){
    {
      float sn[16],cn[16];
      #pragma unroll
      for(int i=0;i<16;++i){ sn[i]=__sinf(xs[i]); cn[i]=__cosf(xs[i]); }
      uint32_t ps[8],pc[8];
      #pragma unroll
      for(int k=0;k<8;++k){
        ps[k]=(uint32_t)rb16(sn[2*k])|((uint32_t)rb16(sn[2*k+1])<<16);
        pc[k]=(uint32_t)rb16(cn[2*k])|((uint32_t)rb16(cn[2*k+1])<<16);
      }
      *(uint4*)&featw[(((2*q  )*16)+c)*8]=make_uint4(ps[0],ps[1],ps[2],ps[3]);
      *(uint4*)&featw[(((2*q+1)*16)+c)*8]=make_uint4(ps[4],ps[5],ps[6],ps[7]);
      *(uint4*)&featw[(((8+2*q)*16)+c)*8]=make_uint4(pc[0],pc[1],pc[2],pc[3]);
      *(uint4*)&featw[(((9+2*q)*16)+c)*8]=make_uint4(pc[4],pc[5],pc[6],pc[7]);
    }
    asm volatile("s_waitcnt lgkmcnt(0)" ::: "memory");
    f32x4 a0={bias[0],bias[0],bias[0],bias[0]};
    f32x4 a1={bias[1],bias[1],bias[1],bias[1]};
    f32x4 a2={bias[2],bias[2],bias[2],bias[2]};
    f32x4 a3={bias[3],bias[3],bias[3],bias[3]};
    #pragma unroll
    for(int kb=0;kb<4;++kb){
      bf16x8 af=__builtin_bit_cast(bf16x8,
                 *(const uint4*)&featw[(((4*kb+gB)*16)+nB)*8]);
      a0=__builtin_amdgcn_mfma_f32_16x16x32_bf16(af,wf[0][kb],a0,0,0,0);
      a1=__builtin_amdgcn_mfma_f32_16x16x32_bf16(af,wf[1][kb],a1,0,0,0);
      a2=__builtin_amdgcn_mfma_f32_16x16x32_bf16(af,wf[2][kb],a2,0,0,0);
      a3=__builtin_amdgcn_mfma_f32_16x16x32_bf16(af,wf[3][kb],a3,0,0,0);
    }
    // sigmoid via v_rcp_f32 (arg in [1,2]: ~1ulp; mu error ~1e-8 abs)
    #pragma unroll
    for(int r=0;r<4;++r){
      muw[(4*gB+r)*SMU +  0 + nB]=FRIC*__builtin_amdgcn_rcpf(1.f+__expf(-a0[r]));
      muw[(4*gB+r)*SMU + 16 + nB]=FRIC*__builtin_amdgcn_rcpf(1.f+__expf(-a1[r]));
      muw[(4*gB+r)*SMU + 32 + nB]=FRIC*__builtin_amdgcn_rcpf(1.f+__expf(-a2[r]));
      muw[(4*gB+r)*SMU + 48 + nB]=FRIC*__builtin_amdgcn_rcpf(1.f+__expf(-a3[r]));
    }
    asm volatile("s_waitcnt lgkmcnt(0)" ::: "memory");
    #pragma unroll
    for(int k=0;k<4;++k){
      float4 t=*(const float4*)&muw[c*SMU+16*q+4*k];
      m[4*k]=t.x; m[4*k+1]=t.y; m[4*k+2]=t.z; m[4*k+3]=t.w;
    }
  };

  friction(mu);                    // mu(x0); carried across half-steps

  for(int s=0;s<steps;++s){
    christoffel(vs,gm);
    {
      #pragma clang fp contract(off)
      #pragma unroll
      for(int i=0;i<16;++i){
        float t  = HDT*(fs[i]-gm[i]);            // np op order
        float num= vs[i]+t;
        float den= (1.f + HDT*mu[i]) + EPS;
        vh[i]= num*__builtin_amdgcn_rcpf(den);   // den~1.0025: rcp err ~1e-7
        float p  = 0.1f*vh[i];                   // matches np's f32 product
        double xx = (double)xs[i] + (double)p;
        double n  = __builtin_rint(xx*0.15915494309189535);
        xs[i] = (float)__builtin_fma(-6.283185307179586, n, xx); // exact mod-2pi
      }
    }
    friction(mu);                  // mu_half == next step's mu (bit-identical)
    christoffel(vh,gm);
    {
      #pragma clang fp contract(off)
      #pragma unroll
      for(int i=0;i<16;++i){
        float t  = HDT*(fs[i]-gm[i]);
        float num= vh[i]+t;
        float den= (1.f + HDT*mu[i]) + EPS;
        vs[i]= num*__builtin_amdgcn_rcpf(den);
      }
    }
  }

  // outputs: (x, v) concatenated; element offset n_rows*64 for v
  const size_t voff=(size_t)n_rows*64;
  if(isbf){
    uint16_t* o=(uint16_t*)outp;
    st16(o,        base, true, xs);
    st16(o+voff,   base, true, vs);
  } else {
    float* o=(float*)outp;
    st16(o,        base, false, xs);
    st16(o+voff,   base, false, vs);
  }
}

extern "C" void kernel_launch(void* const* d_in, const int* in_sizes, int n_in,
                              void* d_out, int out_size, void* d_ws, size_t ws_size,
                              hipStream_t stream) {
  const int n_rows  = in_sizes[0] / 64;
  const int n_tiles = n_rows / 16;
  const int grid    = (n_tiles + 3) / 4;       // 4 waves/block, 1 tile/wave
  leapfrog<<<dim3(grid), dim3(256), 0, stream>>>(
      d_in[0], d_in[1], d_in[2], d_in[3], d_in[4], d_in[5], d_in[6],
      (const int*)d_in[7], d_out, n_rows, n_tiles);
}